// Round 3
// baseline (356.473 us; speedup 1.0000x reference)
//
#include <hip/hip_runtime.h>

// USMSharp R9: FUSED separable conv. Two kernels instead of four:
//   fusedA = hblur(img)->LDS tile -> vblur -> r = img-blur -> rbuf (bf16)
//   fusedB = hblur(mask(rbuf))->LDS tile -> vblur -> blend -> out (f32)
// Each block owns a 72-row x 128-col output tile; phase 1 computes hblur for
// the 122-row haloed tile (1.7x redundant hblur, traded for killing the
// A/Bh HBM round-trip: 375 MB -> 200 MB ideal). LDS written via plain
// ds_write (NOT global_load_lds - R7 lesson). Phase 2 = R6's proven
// register-rolling 9x4 vertical conv, reading LDS.
// All arithmetic orders identical to R6 -> bit-identical output.

#define W 1920
#define H 1080
#define NP 6
#define PLANE (H * W)
#define TOT (NP * PLANE)
#define R 25
#define KS 51
#define TV 9
#define NXT 15
#define NYT 15
#define WU_TOTAL (NXT * NYT * NP)            // 1350
#define WU_PER_XCD ((WU_TOTAL + 7) / 8)      // 169
#define TROW 122                             // 72 out rows + 2*25 halo
#define LSTR 136                             // LDS row stride (ushorts), 272 B: 16B-aligned rows

__device__ __forceinline__ int reflect_idx(int i, int n) {
    if (i < 0) i = -i;
    if (i >= n) i = 2 * n - 2 - i;
    return i;
}
__device__ __forceinline__ float bf2f(unsigned short u) {
    return __uint_as_float(((unsigned int)u) << 16);
}
__device__ __forceinline__ unsigned short f2bf(float f) {  // RNE
    unsigned int x = __float_as_uint(f);
    return (unsigned short)((x + 0x7FFFu + ((x >> 16) & 1u)) >> 16);
}
__device__ __forceinline__ float maskf(float f) {
    return (fabsf(f) * 255.f > 10.f) ? 1.f : 0.f;
}

__global__ void compute_k1(const float* __restrict__ k2d, float* __restrict__ k1) {
    int t = threadIdx.x;
    if (t < KS) {
        float s = 0.f;
        for (int j = 0; j < KS; ++j) s += k2d[t * KS + j];
        k1[t] = s;
    }
}

// acc[o] = sum_k k1[k] * w[o+k+7], window w[i] = x[gx0-32+i], i in [0,80)
// element p contributes to acc[o], o in [max(0,p-57), min(15,p-7)]
#define CONTRIB(P, VV)                                                   \
    {                                                                    \
        const int _p = (P);                                              \
        if (_p >= 7 && _p <= 72) {                                       \
            const int _olo = (_p - 57 > 0) ? _p - 57 : 0;                \
            const int _ohi = (_p - 7 < 15) ? _p - 7 : 15;                \
            _Pragma("unroll") for (int o = _olo; o <= _ohi; ++o)         \
                acc[o] += k1g[_p - 7 - o] * (VV);                        \
        }                                                                \
    }

__device__ __forceinline__ bool decode_wu(int lin, int& p, int& yt, int& xt) {
    int c = lin & 7, j = lin >> 3;
    int wu = c * WU_PER_XCD + j;
    if (wu >= WU_TOTAL) return false;
    p = wu / (NXT * NYT);
    int rem = wu - p * (NXT * NYT);
    yt = rem / NXT;
    xt = rem - yt * NXT;
    return true;
}

// SECOND=false: phase-1 input img (f32), epilogue writes rbuf = img - blur.
// SECOND=true : phase-1 input mask(rbuf bf16), epilogue blends -> out f32.
template <bool SECOND>
__global__ void __launch_bounds__(256, 4)
fused_usm(const float* __restrict__ img, const unsigned short* __restrict__ rbufc,
          const float* __restrict__ k1g, unsigned short* __restrict__ rbufw,
          float* __restrict__ outf) {
    __shared__ unsigned short tile[TROW * LSTR];  // 33184 B
    int p, yt, xt;
    if (!decode_wu(blockIdx.x, p, yt, xt)) return;
    const int y0 = yt * 72;
    const int xbase = xt * 128;
    const size_t pbase = (size_t)p * PLANE;

    // ---- phase 1: hblur rows [y0-R, y0-R+121] (reflect) into LDS ----------
    // 976 chunk-tasks (122 rows x 8 chunks of 16 outputs), strided by 256.
    for (int tq = threadIdx.x; tq < TROW * 8; tq += 256) {
        const int ar = tq >> 3;
        const int ch = tq & 7;
        const int gy = reflect_idx(y0 - R + ar, H);
        const int gx0 = xbase + ch * 16;
        float acc[16];
#pragma unroll
        for (int o = 0; o < 16; ++o) acc[o] = 0.f;
        const bool interior = (gx0 >= 32) && (gx0 + 48 <= W);
        if constexpr (!SECOND) {
            const float* rin = img + pbase + (size_t)gy * W;
            if (interior) {
#pragma unroll
                for (int i = 0; i < 20; ++i) {
                    float4 v = *(const float4*)(rin + gx0 - 32 + 4 * i);
                    CONTRIB(4 * i + 0, v.x);
                    CONTRIB(4 * i + 1, v.y);
                    CONTRIB(4 * i + 2, v.z);
                    CONTRIB(4 * i + 3, v.w);
                }
            } else {
#pragma unroll
                for (int i = 7; i <= 72; ++i) {
                    float vv = rin[reflect_idx(gx0 - 32 + i, W)];
                    CONTRIB(i, vv);
                }
            }
        } else {
            const unsigned short* rin = rbufc + pbase + (size_t)gy * W;
            if (interior) {
#pragma unroll
                for (int i = 0; i < 10; ++i) {
                    uint4 u = *(const uint4*)(rin + gx0 - 32 + 8 * i);
#pragma unroll
                    for (int h = 0; h < 4; ++h) {
                        const unsigned int c = (h == 0) ? u.x : (h == 1) ? u.y : (h == 2) ? u.z : u.w;
                        const float flo = __uint_as_float(c << 16);
                        const float fhi = __uint_as_float(c & 0xffff0000u);
                        CONTRIB(8 * i + 2 * h + 0, maskf(flo));
                        CONTRIB(8 * i + 2 * h + 1, maskf(fhi));
                    }
                }
            } else {
#pragma unroll
                for (int i = 7; i <= 72; ++i) {
                    float vv = maskf(bf2f(rin[reflect_idx(gx0 - 32 + i, W)]));
                    CONTRIB(i, vv);
                }
            }
        }
        // pack 16 bf16 -> 2 x 16B LDS writes (row stride 272 B keeps 16B align)
        uint4 o0, o1;
        o0.x = (unsigned int)f2bf(acc[0]) | ((unsigned int)f2bf(acc[1]) << 16);
        o0.y = (unsigned int)f2bf(acc[2]) | ((unsigned int)f2bf(acc[3]) << 16);
        o0.z = (unsigned int)f2bf(acc[4]) | ((unsigned int)f2bf(acc[5]) << 16);
        o0.w = (unsigned int)f2bf(acc[6]) | ((unsigned int)f2bf(acc[7]) << 16);
        o1.x = (unsigned int)f2bf(acc[8]) | ((unsigned int)f2bf(acc[9]) << 16);
        o1.y = (unsigned int)f2bf(acc[10]) | ((unsigned int)f2bf(acc[11]) << 16);
        o1.z = (unsigned int)f2bf(acc[12]) | ((unsigned int)f2bf(acc[13]) << 16);
        o1.w = (unsigned int)f2bf(acc[14]) | ((unsigned int)f2bf(acc[15]) << 16);
        unsigned short* lp = &tile[ar * LSTR + ch * 16];
        *(uint4*)lp = o0;
        *(uint4*)(lp + 8) = o1;
    }
    __syncthreads();

    // ---- phase 2: register-rolling vertical conv from LDS (R6 order) ------
    const int tx = threadIdx.x & 31, ty = threadIdx.x >> 5;
    const int x4 = xbase + tx * 4;
    float4 acc[TV];
#pragma unroll
    for (int j = 0; j < TV; ++j) acc[j] = make_float4(0.f, 0.f, 0.f, 0.f);
    const unsigned short* trow = &tile[(ty * TV) * LSTR + tx * 4];
#pragma unroll
    for (int u = 0; u < TV + 2 * R; ++u) {
        ushort4 s = *(const ushort4*)(trow + u * LSTR);  // ds_read_b64, imm offset
        float4 v = make_float4(bf2f(s.x), bf2f(s.y), bf2f(s.z), bf2f(s.w));
        const int jlo = (u - 2 * R > 0) ? u - 2 * R : 0;
        const int jhi = (u < TV - 1) ? u : TV - 1;
#pragma unroll
        for (int j = jlo; j <= jhi; ++j) {
            const float k = k1g[u - j];
            acc[j].x += k * v.x; acc[j].y += k * v.y;
            acc[j].z += k * v.z; acc[j].w += k * v.w;
        }
    }

    // ---- epilogue ----------------------------------------------------------
    const int yo = y0 + ty * TV;
#pragma unroll
    for (int j = 0; j < TV; ++j) {
        size_t idx = pbase + (size_t)(yo + j) * W + x4;
        float4 iv = *(const float4*)&img[idx];
        if constexpr (!SECOND) {
            ushort4 rr;
            rr.x = f2bf(iv.x - acc[j].x);
            rr.y = f2bf(iv.y - acc[j].y);
            rr.z = f2bf(iv.z - acc[j].z);
            rr.w = f2bf(iv.w - acc[j].w);
            *(ushort4*)&rbufw[idx] = rr;
        } else {
            ushort4 ru = *(const ushort4*)&rbufc[idx];
            float dx = fminf(fmaxf(iv.x + 0.5f * bf2f(ru.x), 0.f), 1.f) - iv.x;
            float dy = fminf(fmaxf(iv.y + 0.5f * bf2f(ru.y), 0.f), 1.f) - iv.y;
            float dz = fminf(fmaxf(iv.z + 0.5f * bf2f(ru.z), 0.f), 1.f) - iv.z;
            float dw = fminf(fmaxf(iv.w + 0.5f * bf2f(ru.w), 0.f), 1.f) - iv.w;
            float4 o;
            o.x = iv.x + acc[j].x * dx;
            o.y = iv.y + acc[j].y * dy;
            o.z = iv.z + acc[j].z * dz;
            o.w = iv.w + acc[j].w * dw;
            *(float4*)&outf[idx] = o;
        }
    }
}

extern "C" void kernel_launch(void* const* d_in, const int* in_sizes, int n_in,
                              void* d_out, int out_size, void* d_ws, size_t ws_size,
                              hipStream_t stream) {
    const float* img = (const float*)d_in[0];
    const float* k2d = (const float*)d_in[1];
    float* out = (float*)d_out;

    unsigned short* rbuf = (unsigned short*)d_ws;  // residual bf16
    float* k1 = (float*)(rbuf + TOT);

    const int grid = 8 * WU_PER_XCD;  // 1352

    hipLaunchKernelGGL(compute_k1, dim3(1), dim3(64), 0, stream, k2d, k1);
    hipLaunchKernelGGL((fused_usm<false>), dim3(grid), dim3(256), 0, stream,
                       img, rbuf, k1, rbuf, out);
    hipLaunchKernelGGL((fused_usm<true>), dim3(grid), dim3(256), 0, stream,
                       img, rbuf, k1, rbuf, out);
}

// Round 4
// 226.706 us; speedup vs baseline: 1.5724x; 1.5724x over previous
//
#include <hip/hip_runtime.h>

// USMSharp R10: R6 structure (4 kernels, best measured 228us), re-tiled for
// occupancy. R7 (LDS DMA) and R8 (reg batching) both regressed; R9 (fusion)
// amplified traffic. This round changes ONLY launch geometry:
//  - vblur: 36x128 tiles, 128-thread (32x4) blocks -> grid 2704 (was 1352x256),
//    10.6 blocks/CU, 2-wave packing granularity. Per-output arithmetic and
//    the TV=9 register-rolling loop are byte-identical to R6.
//  - hblur: same thread->task map, 128-thread blocks -> grid 6076.
// No __launch_bounds__ (R8 lesson: it provoked AGPR shuffling).
// K1 hblur16(img f32)->A bf16 ; K2 vblur_r(A) -> r=img-blur bf16
// K3 hblur16(mask(|r|*255>10))->Bh bf16 (aliases A) ; K4 vblur_blend+blend->out.

#define W 1920
#define H 1080
#define NP 6
#define PLANE (H * W)
#define TOT (NP * PLANE)
#define R 25
#define KS 51
#define TV 9
#define NXT 15
#define NYT 30                        // y-tiles of 36 rows (was 15 x 72)
#define WU_TOTAL (NXT * NYT * NP)     // 2700
#define WU_PER_XCD ((WU_TOTAL + 7) / 8)  // 338
#define NROWS (H * NP)                // 6480
#define NI (NROWS * 116)              // interior threads (chunks 2..117)
#define NBI ((NI + 127) / 128)        // 5873  (128-thread blocks)
#define NB (NROWS * 4)                // boundary threads (chunks 0,1,118,119)
#define NBB ((NB + 127) / 128)        // 203

__device__ __forceinline__ int reflect_idx(int i, int n) {
    if (i < 0) i = -i;
    if (i >= n) i = 2 * n - 2 - i;
    return i;
}
__device__ __forceinline__ float bf2f(unsigned short u) {
    return __uint_as_float(((unsigned int)u) << 16);
}
__device__ __forceinline__ unsigned short f2bf(float f) {  // RNE
    unsigned int x = __float_as_uint(f);
    return (unsigned short)((x + 0x7FFFu + ((x >> 16) & 1u)) >> 16);
}
__device__ __forceinline__ float maskf(float f) {
    return (fabsf(f) * 255.f > 10.f) ? 1.f : 0.f;
}

__global__ void compute_k1(const float* __restrict__ k2d, float* __restrict__ k1) {
    int t = threadIdx.x;
    if (t < KS) {
        float s = 0.f;
        for (int j = 0; j < KS; ++j) s += k2d[t * KS + j];
        k1[t] = s;
    }
}

// acc[o] = sum_k k1[k] * w[o+k+7], window w[i] = x[c0-32+i], i in [0,80)
// element p contributes to acc[o], o in [max(0,p-57), min(15,p-7)]
#define CONTRIB(P, VV)                                                   \
    {                                                                    \
        const int _p = (P);                                              \
        if (_p >= 7 && _p <= 72) {                                       \
            const int _olo = (_p - 57 > 0) ? _p - 57 : 0;                \
            const int _ohi = (_p - 7 < 15) ? _p - 7 : 15;                \
            _Pragma("unroll") for (int o = _olo; o <= _ohi; ++o)         \
                acc[o] += k1g[_p - 7 - o] * (VV);                        \
        }                                                                \
    }

template <bool MASK>
__global__ void hblur16(const void* __restrict__ inv, unsigned short* __restrict__ out,
                        const float* __restrict__ k1g) {
    const int b = blockIdx.x;
    float acc[16];
#pragma unroll
    for (int o = 0; o < 16; ++o) acc[o] = 0.f;
    int row, c0;
    if (b < NBI) {  // ---- interior: chunks 2..117, aligned vector loads ----
        const int t = b * 128 + threadIdx.x;
        if (t >= NI) return;
        row = t / 116;
        c0 = (2 + (t - row * 116)) * 16;
        if constexpr (!MASK) {
            const float* rin = (const float*)inv + (size_t)row * W;
#pragma unroll
            for (int i = 0; i < 20; ++i) {
                float4 v = *(const float4*)(rin + c0 - 32 + 4 * i);
                CONTRIB(4 * i + 0, v.x);
                CONTRIB(4 * i + 1, v.y);
                CONTRIB(4 * i + 2, v.z);
                CONTRIB(4 * i + 3, v.w);
            }
        } else {
            const unsigned short* rin = (const unsigned short*)inv + (size_t)row * W;
#pragma unroll
            for (int i = 0; i < 10; ++i) {
                uint4 u = *(const uint4*)(rin + c0 - 32 + 8 * i);
#pragma unroll
                for (int h = 0; h < 4; ++h) {
                    const unsigned int c = (h == 0) ? u.x : (h == 1) ? u.y : (h == 2) ? u.z : u.w;
                    const float flo = __uint_as_float(c << 16);
                    const float fhi = __uint_as_float(c & 0xffff0000u);
                    CONTRIB(8 * i + 2 * h + 0, maskf(flo));
                    CONTRIB(8 * i + 2 * h + 1, maskf(fhi));
                }
            }
        }
    } else {  // ---- boundary: chunks 0,1,118,119, scalar reflect loads ----
        const int t = (b - NBI) * 128 + threadIdx.x;
        if (t >= NB) return;
        row = t >> 2;
        const int q = t & 3;
        c0 = ((q < 2) ? q : q + 116) * 16;
        if constexpr (!MASK) {
            const float* rin = (const float*)inv + (size_t)row * W;
#pragma unroll
            for (int i = 7; i <= 72; ++i) {
                float vv = rin[reflect_idx(c0 - 32 + i, W)];
                CONTRIB(i, vv);
            }
        } else {
            const unsigned short* rin = (const unsigned short*)inv + (size_t)row * W;
#pragma unroll
            for (int i = 7; i <= 72; ++i) {
                float vv = maskf(bf2f(rin[reflect_idx(c0 - 32 + i, W)]));
                CONTRIB(i, vv);
            }
        }
    }
    // pack 16 bf16 -> 2 x 16B stores
    uint4 o0, o1;
    o0.x = (unsigned int)f2bf(acc[0]) | ((unsigned int)f2bf(acc[1]) << 16);
    o0.y = (unsigned int)f2bf(acc[2]) | ((unsigned int)f2bf(acc[3]) << 16);
    o0.z = (unsigned int)f2bf(acc[4]) | ((unsigned int)f2bf(acc[5]) << 16);
    o0.w = (unsigned int)f2bf(acc[6]) | ((unsigned int)f2bf(acc[7]) << 16);
    o1.x = (unsigned int)f2bf(acc[8]) | ((unsigned int)f2bf(acc[9]) << 16);
    o1.y = (unsigned int)f2bf(acc[10]) | ((unsigned int)f2bf(acc[11]) << 16);
    o1.z = (unsigned int)f2bf(acc[12]) | ((unsigned int)f2bf(acc[13]) << 16);
    o1.w = (unsigned int)f2bf(acc[14]) | ((unsigned int)f2bf(acc[15]) << 16);
    unsigned short* op = out + (size_t)row * W + c0;
    *(uint4*)op = o0;
    *(uint4*)(op + 8) = o1;
}

// ---- vertical conv: register rolling, 9 rows x 4 cols per thread (R6) -----
__device__ __forceinline__ bool decode_wu(int lin, int& p, int& yt, int& xt) {
    int c = lin & 7, j = lin >> 3;
    int wu = c * WU_PER_XCD + j;
    if (wu >= WU_TOTAL) return false;
    p = wu / (NXT * NYT);
    int rem = wu - p * (NXT * NYT);
    yt = rem / NXT;
    xt = rem - yt * NXT;
    return true;
}

__device__ __forceinline__ void vconv9(const unsigned short* __restrict__ Ap, int x4, int y0,
                                       const float* __restrict__ k1g, float4 acc[TV]) {
#pragma unroll
    for (int j = 0; j < TV; ++j) acc[j] = make_float4(0.f, 0.f, 0.f, 0.f);
    if (y0 >= R && y0 + TV - 1 + R < H) {
        const unsigned short* p = Ap + (size_t)(y0 - R) * W + x4;
#pragma unroll
        for (int u = 0; u < TV + 2 * R; ++u) {
            ushort4 s = *(const ushort4*)p;
            p += W;
            float4 v = make_float4(bf2f(s.x), bf2f(s.y), bf2f(s.z), bf2f(s.w));
            const int jlo = (u - 2 * R > 0) ? u - 2 * R : 0;
            const int jhi = (u < TV - 1) ? u : TV - 1;
#pragma unroll
            for (int j = jlo; j <= jhi; ++j) {
                const float k = k1g[u - j];
                acc[j].x += k * v.x; acc[j].y += k * v.y;
                acc[j].z += k * v.z; acc[j].w += k * v.w;
            }
        }
    } else {
#pragma unroll
        for (int u = 0; u < TV + 2 * R; ++u) {
            int yy = reflect_idx(y0 - R + u, H);
            ushort4 s = *(const ushort4*)(Ap + (size_t)yy * W + x4);
            float4 v = make_float4(bf2f(s.x), bf2f(s.y), bf2f(s.z), bf2f(s.w));
            const int jlo = (u - 2 * R > 0) ? u - 2 * R : 0;
            const int jhi = (u < TV - 1) ? u : TV - 1;
#pragma unroll
            for (int j = jlo; j <= jhi; ++j) {
                const float k = k1g[u - j];
                acc[j].x += k * v.x; acc[j].y += k * v.y;
                acc[j].z += k * v.z; acc[j].w += k * v.w;
            }
        }
    }
}

__global__ void vblur_r(const unsigned short* __restrict__ A, const float* __restrict__ img,
                        const float* __restrict__ k1g, unsigned short* __restrict__ rbuf) {
    int p, yt, xt;
    if (!decode_wu(blockIdx.x, p, yt, xt)) return;
    const int tx = threadIdx.x & 31, ty = threadIdx.x >> 5;  // 128 thr: ty 0..3
    const int x4 = xt * 128 + tx * 4;
    const int y0 = yt * 36 + ty * TV;
    float4 acc[TV];
    vconv9(A + (size_t)p * PLANE, x4, y0, k1g, acc);
#pragma unroll
    for (int j = 0; j < TV; ++j) {
        size_t idx = (size_t)p * PLANE + (size_t)(y0 + j) * W + x4;
        float4 iv = *(const float4*)&img[idx];
        ushort4 rr;
        rr.x = f2bf(iv.x - acc[j].x);
        rr.y = f2bf(iv.y - acc[j].y);
        rr.z = f2bf(iv.z - acc[j].z);
        rr.w = f2bf(iv.w - acc[j].w);
        *(ushort4*)&rbuf[idx] = rr;
    }
}

__global__ void vblur_blend(const unsigned short* __restrict__ Bh, const float* __restrict__ img,
                            const unsigned short* __restrict__ rbuf,
                            const float* __restrict__ k1g, float* __restrict__ out) {
    int p, yt, xt;
    if (!decode_wu(blockIdx.x, p, yt, xt)) return;
    const int tx = threadIdx.x & 31, ty = threadIdx.x >> 5;  // 128 thr: ty 0..3
    const int x4 = xt * 128 + tx * 4;
    const int y0 = yt * 36 + ty * TV;
    float4 acc[TV];
    vconv9(Bh + (size_t)p * PLANE, x4, y0, k1g, acc);
#pragma unroll
    for (int j = 0; j < TV; ++j) {
        size_t idx = (size_t)p * PLANE + (size_t)(y0 + j) * W + x4;
        float4 iv = *(const float4*)&img[idx];
        ushort4 ru = *(const ushort4*)&rbuf[idx];
        float dx = fminf(fmaxf(iv.x + 0.5f * bf2f(ru.x), 0.f), 1.f) - iv.x;
        float dy = fminf(fmaxf(iv.y + 0.5f * bf2f(ru.y), 0.f), 1.f) - iv.y;
        float dz = fminf(fmaxf(iv.z + 0.5f * bf2f(ru.z), 0.f), 1.f) - iv.z;
        float dw = fminf(fmaxf(iv.w + 0.5f * bf2f(ru.w), 0.f), 1.f) - iv.w;
        float4 o;
        o.x = iv.x + acc[j].x * dx;
        o.y = iv.y + acc[j].y * dy;
        o.z = iv.z + acc[j].z * dz;
        o.w = iv.w + acc[j].w * dw;
        *(float4*)&out[idx] = o;
    }
}

extern "C" void kernel_launch(void* const* d_in, const int* in_sizes, int n_in,
                              void* d_out, int out_size, void* d_ws, size_t ws_size,
                              hipStream_t stream) {
    const float* img = (const float*)d_in[0];
    const float* k2d = (const float*)d_in[1];
    float* out = (float*)d_out;

    unsigned short* AB = (unsigned short*)d_ws;  // A, later Bh
    unsigned short* rbuf = AB + TOT;             // residual bf16
    float* k1 = (float*)(rbuf + TOT);

    const int gridHB = NBI + NBB;        // 6076  (128-thread blocks)
    const int gridVB = 8 * WU_PER_XCD;   // 2704  (128-thread blocks)

    hipLaunchKernelGGL(compute_k1, dim3(1), dim3(64), 0, stream, k2d, k1);
    hipLaunchKernelGGL((hblur16<false>), dim3(gridHB), dim3(128), 0, stream, (const void*)img, AB, k1);
    hipLaunchKernelGGL(vblur_r, dim3(gridVB), dim3(128), 0, stream, AB, img, k1, rbuf);
    hipLaunchKernelGGL((hblur16<true>), dim3(gridHB), dim3(128), 0, stream, (const void*)rbuf, AB, k1);
    hipLaunchKernelGGL(vblur_blend, dim3(gridVB), dim3(128), 0, stream, AB, img, rbuf, k1, out);
}

// Round 5
// 200.217 us; speedup vs baseline: 1.7804x; 1.1323x over previous
//
#include <hip/hip_runtime.h>

// USMSharp R11: R10 structure; vblur re-decomposed for total-wave count.
// R10 lesson: doubling blocks while halving waves/block kept total waves at
// 5408 (21/CU peak) -> occupancy pinned at ~25%, no change. This round
// shrinks per-thread work TV=9 -> TV=5 (36 px -> 20 px/thread): 9720 waves
// (38/CU available, 32/CU resident cap) -> latency hidden by TLP.
// Vertical redundancy 6.6x -> 11x, but re-reads are L2/L3 hits (FETCH has
// stayed at compulsory ~75MB all session). Per-output tap order (k ascending)
// is TV-independent -> bit-identical output.
// K1 hblur16(img f32)->A bf16 ; K2 vblur_r(A) -> r=img-blur bf16
// K3 hblur16(mask(|r|*255>10))->Bh bf16 (aliases A) ; K4 vblur_blend+blend->out.

#define W 1920
#define H 1080
#define NP 6
#define PLANE (H * W)
#define TOT (NP * PLANE)
#define R 25
#define KS 51
#define TV 5                          // rows per thread (was 9)
#define TBR 20                        // rows per block = 4 ty-groups * TV
#define NXT 15
#define NYT 54                        // 1080 / 20
#define WU_TOTAL (NXT * NYT * NP)     // 4860
#define WU_PER_XCD ((WU_TOTAL + 7) / 8)  // 608
#define NROWS (H * NP)                // 6480
#define NI (NROWS * 116)              // interior threads (chunks 2..117)
#define NBI ((NI + 127) / 128)        // 5873  (128-thread blocks)
#define NB (NROWS * 4)                // boundary threads (chunks 0,1,118,119)
#define NBB ((NB + 127) / 128)        // 203

__device__ __forceinline__ int reflect_idx(int i, int n) {
    if (i < 0) i = -i;
    if (i >= n) i = 2 * n - 2 - i;
    return i;
}
__device__ __forceinline__ float bf2f(unsigned short u) {
    return __uint_as_float(((unsigned int)u) << 16);
}
__device__ __forceinline__ unsigned short f2bf(float f) {  // RNE
    unsigned int x = __float_as_uint(f);
    return (unsigned short)((x + 0x7FFFu + ((x >> 16) & 1u)) >> 16);
}
__device__ __forceinline__ float maskf(float f) {
    return (fabsf(f) * 255.f > 10.f) ? 1.f : 0.f;
}

__global__ void compute_k1(const float* __restrict__ k2d, float* __restrict__ k1) {
    int t = threadIdx.x;
    if (t < KS) {
        float s = 0.f;
        for (int j = 0; j < KS; ++j) s += k2d[t * KS + j];
        k1[t] = s;
    }
}

// acc[o] = sum_k k1[k] * w[o+k+7], window w[i] = x[c0-32+i], i in [0,80)
// element p contributes to acc[o], o in [max(0,p-57), min(15,p-7)]
#define CONTRIB(P, VV)                                                   \
    {                                                                    \
        const int _p = (P);                                              \
        if (_p >= 7 && _p <= 72) {                                       \
            const int _olo = (_p - 57 > 0) ? _p - 57 : 0;                \
            const int _ohi = (_p - 7 < 15) ? _p - 7 : 15;                \
            _Pragma("unroll") for (int o = _olo; o <= _ohi; ++o)         \
                acc[o] += k1g[_p - 7 - o] * (VV);                        \
        }                                                                \
    }

template <bool MASK>
__global__ void hblur16(const void* __restrict__ inv, unsigned short* __restrict__ out,
                        const float* __restrict__ k1g) {
    const int b = blockIdx.x;
    float acc[16];
#pragma unroll
    for (int o = 0; o < 16; ++o) acc[o] = 0.f;
    int row, c0;
    if (b < NBI) {  // ---- interior: chunks 2..117, aligned vector loads ----
        const int t = b * 128 + threadIdx.x;
        if (t >= NI) return;
        row = t / 116;
        c0 = (2 + (t - row * 116)) * 16;
        if constexpr (!MASK) {
            const float* rin = (const float*)inv + (size_t)row * W;
#pragma unroll
            for (int i = 0; i < 20; ++i) {
                float4 v = *(const float4*)(rin + c0 - 32 + 4 * i);
                CONTRIB(4 * i + 0, v.x);
                CONTRIB(4 * i + 1, v.y);
                CONTRIB(4 * i + 2, v.z);
                CONTRIB(4 * i + 3, v.w);
            }
        } else {
            const unsigned short* rin = (const unsigned short*)inv + (size_t)row * W;
#pragma unroll
            for (int i = 0; i < 10; ++i) {
                uint4 u = *(const uint4*)(rin + c0 - 32 + 8 * i);
#pragma unroll
                for (int h = 0; h < 4; ++h) {
                    const unsigned int c = (h == 0) ? u.x : (h == 1) ? u.y : (h == 2) ? u.z : u.w;
                    const float flo = __uint_as_float(c << 16);
                    const float fhi = __uint_as_float(c & 0xffff0000u);
                    CONTRIB(8 * i + 2 * h + 0, maskf(flo));
                    CONTRIB(8 * i + 2 * h + 1, maskf(fhi));
                }
            }
        }
    } else {  // ---- boundary: chunks 0,1,118,119, scalar reflect loads ----
        const int t = (b - NBI) * 128 + threadIdx.x;
        if (t >= NB) return;
        row = t >> 2;
        const int q = t & 3;
        c0 = ((q < 2) ? q : q + 116) * 16;
        if constexpr (!MASK) {
            const float* rin = (const float*)inv + (size_t)row * W;
#pragma unroll
            for (int i = 7; i <= 72; ++i) {
                float vv = rin[reflect_idx(c0 - 32 + i, W)];
                CONTRIB(i, vv);
            }
        } else {
            const unsigned short* rin = (const unsigned short*)inv + (size_t)row * W;
#pragma unroll
            for (int i = 7; i <= 72; ++i) {
                float vv = maskf(bf2f(rin[reflect_idx(c0 - 32 + i, W)]));
                CONTRIB(i, vv);
            }
        }
    }
    // pack 16 bf16 -> 2 x 16B stores
    uint4 o0, o1;
    o0.x = (unsigned int)f2bf(acc[0]) | ((unsigned int)f2bf(acc[1]) << 16);
    o0.y = (unsigned int)f2bf(acc[2]) | ((unsigned int)f2bf(acc[3]) << 16);
    o0.z = (unsigned int)f2bf(acc[4]) | ((unsigned int)f2bf(acc[5]) << 16);
    o0.w = (unsigned int)f2bf(acc[6]) | ((unsigned int)f2bf(acc[7]) << 16);
    o1.x = (unsigned int)f2bf(acc[8]) | ((unsigned int)f2bf(acc[9]) << 16);
    o1.y = (unsigned int)f2bf(acc[10]) | ((unsigned int)f2bf(acc[11]) << 16);
    o1.z = (unsigned int)f2bf(acc[12]) | ((unsigned int)f2bf(acc[13]) << 16);
    o1.w = (unsigned int)f2bf(acc[14]) | ((unsigned int)f2bf(acc[15]) << 16);
    unsigned short* op = out + (size_t)row * W + c0;
    *(uint4*)op = o0;
    *(uint4*)(op + 8) = o1;
}

// ---- vertical conv: register rolling, TV rows x 4 cols per thread ---------
__device__ __forceinline__ bool decode_wu(int lin, int& p, int& yt, int& xt) {
    int c = lin & 7, j = lin >> 3;
    int wu = c * WU_PER_XCD + j;
    if (wu >= WU_TOTAL) return false;
    p = wu / (NXT * NYT);
    int rem = wu - p * (NXT * NYT);
    yt = rem / NXT;
    xt = rem - yt * NXT;
    return true;
}

__device__ __forceinline__ void vconvT(const unsigned short* __restrict__ Ap, int x4, int y0,
                                       const float* __restrict__ k1g, float4 acc[TV]) {
#pragma unroll
    for (int j = 0; j < TV; ++j) acc[j] = make_float4(0.f, 0.f, 0.f, 0.f);
    if (y0 >= R && y0 + TV - 1 + R < H) {
        const unsigned short* p = Ap + (size_t)(y0 - R) * W + x4;
#pragma unroll
        for (int u = 0; u < TV + 2 * R; ++u) {
            ushort4 s = *(const ushort4*)p;
            p += W;
            float4 v = make_float4(bf2f(s.x), bf2f(s.y), bf2f(s.z), bf2f(s.w));
            const int jlo = (u - 2 * R > 0) ? u - 2 * R : 0;
            const int jhi = (u < TV - 1) ? u : TV - 1;
#pragma unroll
            for (int j = jlo; j <= jhi; ++j) {
                const float k = k1g[u - j];
                acc[j].x += k * v.x; acc[j].y += k * v.y;
                acc[j].z += k * v.z; acc[j].w += k * v.w;
            }
        }
    } else {
#pragma unroll
        for (int u = 0; u < TV + 2 * R; ++u) {
            int yy = reflect_idx(y0 - R + u, H);
            ushort4 s = *(const ushort4*)(Ap + (size_t)yy * W + x4);
            float4 v = make_float4(bf2f(s.x), bf2f(s.y), bf2f(s.z), bf2f(s.w));
            const int jlo = (u - 2 * R > 0) ? u - 2 * R : 0;
            const int jhi = (u < TV - 1) ? u : TV - 1;
#pragma unroll
            for (int j = jlo; j <= jhi; ++j) {
                const float k = k1g[u - j];
                acc[j].x += k * v.x; acc[j].y += k * v.y;
                acc[j].z += k * v.z; acc[j].w += k * v.w;
            }
        }
    }
}

__global__ void vblur_r(const unsigned short* __restrict__ A, const float* __restrict__ img,
                        const float* __restrict__ k1g, unsigned short* __restrict__ rbuf) {
    int p, yt, xt;
    if (!decode_wu(blockIdx.x, p, yt, xt)) return;
    const int tx = threadIdx.x & 31, ty = threadIdx.x >> 5;  // 128 thr: ty 0..3
    const int x4 = xt * 128 + tx * 4;
    const int y0 = yt * TBR + ty * TV;
    float4 acc[TV];
    vconvT(A + (size_t)p * PLANE, x4, y0, k1g, acc);
#pragma unroll
    for (int j = 0; j < TV; ++j) {
        size_t idx = (size_t)p * PLANE + (size_t)(y0 + j) * W + x4;
        float4 iv = *(const float4*)&img[idx];
        ushort4 rr;
        rr.x = f2bf(iv.x - acc[j].x);
        rr.y = f2bf(iv.y - acc[j].y);
        rr.z = f2bf(iv.z - acc[j].z);
        rr.w = f2bf(iv.w - acc[j].w);
        *(ushort4*)&rbuf[idx] = rr;
    }
}

__global__ void vblur_blend(const unsigned short* __restrict__ Bh, const float* __restrict__ img,
                            const unsigned short* __restrict__ rbuf,
                            const float* __restrict__ k1g, float* __restrict__ out) {
    int p, yt, xt;
    if (!decode_wu(blockIdx.x, p, yt, xt)) return;
    const int tx = threadIdx.x & 31, ty = threadIdx.x >> 5;  // 128 thr: ty 0..3
    const int x4 = xt * 128 + tx * 4;
    const int y0 = yt * TBR + ty * TV;
    float4 acc[TV];
    vconvT(Bh + (size_t)p * PLANE, x4, y0, k1g, acc);
#pragma unroll
    for (int j = 0; j < TV; ++j) {
        size_t idx = (size_t)p * PLANE + (size_t)(y0 + j) * W + x4;
        float4 iv = *(const float4*)&img[idx];
        ushort4 ru = *(const ushort4*)&rbuf[idx];
        float dx = fminf(fmaxf(iv.x + 0.5f * bf2f(ru.x), 0.f), 1.f) - iv.x;
        float dy = fminf(fmaxf(iv.y + 0.5f * bf2f(ru.y), 0.f), 1.f) - iv.y;
        float dz = fminf(fmaxf(iv.z + 0.5f * bf2f(ru.z), 0.f), 1.f) - iv.z;
        float dw = fminf(fmaxf(iv.w + 0.5f * bf2f(ru.w), 0.f), 1.f) - iv.w;
        float4 o;
        o.x = iv.x + acc[j].x * dx;
        o.y = iv.y + acc[j].y * dy;
        o.z = iv.z + acc[j].z * dz;
        o.w = iv.w + acc[j].w * dw;
        *(float4*)&out[idx] = o;
    }
}

extern "C" void kernel_launch(void* const* d_in, const int* in_sizes, int n_in,
                              void* d_out, int out_size, void* d_ws, size_t ws_size,
                              hipStream_t stream) {
    const float* img = (const float*)d_in[0];
    const float* k2d = (const float*)d_in[1];
    float* out = (float*)d_out;

    unsigned short* AB = (unsigned short*)d_ws;  // A, later Bh
    unsigned short* rbuf = AB + TOT;             // residual bf16
    float* k1 = (float*)(rbuf + TOT);

    const int gridHB = NBI + NBB;        // 6076  (128-thread blocks)
    const int gridVB = 8 * WU_PER_XCD;   // 4864  (128-thread blocks)

    hipLaunchKernelGGL(compute_k1, dim3(1), dim3(64), 0, stream, k2d, k1);
    hipLaunchKernelGGL((hblur16<false>), dim3(gridHB), dim3(128), 0, stream, (const void*)img, AB, k1);
    hipLaunchKernelGGL(vblur_r, dim3(gridVB), dim3(128), 0, stream, AB, img, k1, rbuf);
    hipLaunchKernelGGL((hblur16<true>), dim3(gridHB), dim3(128), 0, stream, (const void*)rbuf, AB, k1);
    hipLaunchKernelGGL(vblur_blend, dim3(gridVB), dim3(128), 0, stream, AB, img, rbuf, k1, out);
}